// Round 17
// baseline (157.087 us; speedup 1.0000x reference)
//
#include <hip/hip_runtime.h>
#include <stdint.h>

#define N_Q    4096
#define D_K    512
#define D_OUT  16384
#define NCLUST 256

// GEMM: 256x128 tile, BK=32, 4 waves (2M x 2N), per-wave 128x64 (acc 8x4).
// Ring-3 slots of 24 KB = 72 KB -> 2 WG/CU, T2 swizzle, setprio, XCD panel
// mapping, LDS-transposed full-line NT epilogue (NT>plain proven by r16 A/B).
// Round-17 lever: W converted IN-GEMM (reg-staged B: f32 asm loads -> cvt_pk
// -> ds_write, manual vmcnt FIFO) -> the 14us W-prep kernel disappears.
// A staging unchanged (global_load_lds from A_bf, distance 2).
#define BM 256
#define BN 128
#define BK 32
#define NT (D_K / BK)   // 16 K-tiles
#define SCP 132         // sC row stride in floats (non-pow2: conflict-free)

typedef __attribute__((ext_vector_type(4))) float f32x4;
typedef __attribute__((ext_vector_type(8))) short bf16x8;

__device__ __forceinline__ uint32_t f2bf(float f) {
  uint32_t u = __float_as_uint(f);
  u += 0x7FFFu + ((u >> 16) & 1u);
  return u >> 16;
}

#define GLOAD_LDS16(g, l)                                         \
  __builtin_amdgcn_global_load_lds(                               \
      (const __attribute__((address_space(1))) void*)(g),         \
      (__attribute__((address_space(3))) void*)(l), 16, 0, 0)

// f32x4 global load, invisible to compiler's waitcnt pass (manual vmcnt FIFO)
__device__ __forceinline__ f32x4 gloadf4(const float* p) {
  f32x4 r;
  asm volatile("global_load_dwordx4 %0, %1, off" : "=v"(r) : "v"(p));
  return r;
}
// packed f32 pair -> bf16x2 (RNE)
__device__ __forceinline__ uint32_t cvtpk(float lo, float hi) {
  uint32_t r;
  asm("v_cvt_pk_bf16_f32 %0, %1, %2" : "=v"(r) : "v"(lo), "v"(hi));
  return r;
}

// tile-top: counted vmcnt + lgkm drain (ds_write visibility) + barrier
#define WAIT_BAR_LG(N) do {                                                     \
    asm volatile("s_waitcnt vmcnt(" #N ") lgkmcnt(0)\n\ts_barrier" ::: "memory"); \
    __builtin_amdgcn_sched_barrier(0);                                          \
  } while (0)
#define LBAR() asm volatile("s_waitcnt lgkmcnt(0)\n\ts_barrier" ::: "memory")
#define CFENCE() asm volatile("" ::: "memory")

// centroid transpose + cmask zero (tiny; routing depends on it)
__global__ __launch_bounds__(256) void cent_kernel(const float* __restrict__ cent,
                                                   float4* __restrict__ centT4,
                                                   float* __restrict__ cmask) {
  if (blockIdx.x == 0) cmask[threadIdx.x] = 0.0f;
  int idx = blockIdx.x * 256 + threadIdx.x;
  int k4 = idx & 127, c = idx >> 7;
  float4 v = *reinterpret_cast<const float4*>(&cent[(size_t)c * D_K + k4 * 4]);
  centT4[(size_t)k4 * NCLUST + c] = v;
}

// 8 queries/block; thread t owns centroid t; fused A f32->bf16 convert.
// f32 routing math throughout (threshold booleans must not flip).
__global__ __launch_bounds__(256) void routing_kernel(const float* __restrict__ input,
                                                      const float4* __restrict__ centT4,
                                                      float* __restrict__ qmask,
                                                      float* __restrict__ cmask,
                                                      ushort* __restrict__ A_bf) {
  __shared__ float lgs[8][NCLUST];
  int c = threadIdx.x;
  int q0 = blockIdx.x * 8;
  const float* __restrict__ inp = input + (size_t)q0 * D_K;

  {
    const float4* s4 = reinterpret_cast<const float4*>(inp) + c * 4;
    float4 x0 = s4[0], x1 = s4[1], x2 = s4[2], x3 = s4[3];
    uint4 o0, o1;
    o0.x = f2bf(x0.x) | (f2bf(x0.y) << 16);
    o0.y = f2bf(x0.z) | (f2bf(x0.w) << 16);
    o0.z = f2bf(x1.x) | (f2bf(x1.y) << 16);
    o0.w = f2bf(x1.z) | (f2bf(x1.w) << 16);
    o1.x = f2bf(x2.x) | (f2bf(x2.y) << 16);
    o1.y = f2bf(x2.z) | (f2bf(x2.w) << 16);
    o1.z = f2bf(x3.x) | (f2bf(x3.y) << 16);
    o1.w = f2bf(x3.z) | (f2bf(x3.w) << 16);
    uint4* dst = reinterpret_cast<uint4*>(A_bf + (size_t)q0 * D_K);
    dst[c * 2] = o0;
    dst[c * 2 + 1] = o1;
  }

  float acc[8] = {0, 0, 0, 0, 0, 0, 0, 0};
  for (int k4 = 0; k4 < D_K / 4; ++k4) {
    float4 v = centT4[(size_t)k4 * NCLUST + c];
#pragma unroll
    for (int q = 0; q < 8; ++q) {
      float4 r = *reinterpret_cast<const float4*>(&inp[q * D_K + k4 * 4]);  // uniform addr
      acc[q] += v.x * r.x + v.y * r.y + v.z * r.z + v.w * r.w;
    }
  }
#pragma unroll
  for (int q = 0; q < 8; ++q) lgs[q][c] = acc[q] * 10.0f;  // /TEMPERATURE
  __syncthreads();

  int wave = c >> 6, lane = c & 63;
#pragma unroll
  for (int qq = 0; qq < 2; ++qq) {
    int q = wave * 2 + qq;
    float4 lv = *reinterpret_cast<const float4*>(&lgs[q][lane * 4]);
    float m = fmaxf(fmaxf(lv.x, lv.y), fmaxf(lv.z, lv.w));
#pragma unroll
    for (int off = 32; off > 0; off >>= 1) m = fmaxf(m, __shfl_xor(m, off));
    float e0 = expf(lv.x - m), e1 = expf(lv.y - m), e2 = expf(lv.z - m), e3 = expf(lv.w - m);
    float s = e0 + e1 + e2 + e3;
#pragma unroll
    for (int off = 32; off > 0; off >>= 1) s += __shfl_xor(s, off);
    float thr = 0.01f * s;
    bool a0 = e0 > thr, a1 = e1 > thr, a2 = e2 > thr, a3 = e3 > thr;
    if (a0) cmask[lane * 4 + 0] = 1.0f;  // benign races: all writers store 1.0
    if (a1) cmask[lane * 4 + 1] = 1.0f;
    if (a2) cmask[lane * 4 + 2] = 1.0f;
    if (a3) cmask[lane * 4 + 3] = 1.0f;
    unsigned long long any = __ballot(a0 | a1 | a2 | a3);
    if (lane == 0) qmask[q0 + q] = any ? 1.0f : 0.0f;
  }
}

__global__ __launch_bounds__(256, 2) void gemm_masked_kernel(
    const ushort* __restrict__ A, const float* __restrict__ Wf,
    const float* __restrict__ bias, const int* __restrict__ assign,
    const float* __restrict__ qmask, const float* __restrict__ cmask,
    float* __restrict__ C) {
  // LDS 72 KB: 3 slots of 24 KB = {A 16 KB (4 x 4KB row-groups) | B 8 KB}.
  // Epilogue reuses front 33.8 KB as sC[64][SCP]. 2 WG/CU.
  __shared__ __align__(16) char smem[73728];

  int tid = threadIdx.x;
  int wave = tid >> 6, lane = tid & 63;

  // XCD mapping: xcd = bid&7 owns ntiles [16x,16x+16); ntile fast within XCD
  // (W f32 panel set 4 MB/XCD ~ L2-resident). 2048 = 8*16*16 -> bijective.
  int bid = blockIdx.x;
  int idx = bid >> 3;                         // 0..255
  int ntile = (bid & 7) * 16 + (idx & 15);    // 0..127
  int mtile = idx >> 4;                       // 0..15
  int m0 = mtile * BM, n0 = ntile * BN;

  int wr = wave >> 1, wc = wave & 1;  // 2x2 wave grid; per-wave C: 128x64

  // A staging (unchanged): LDS (row,kg) <- global (row, kg ^ ((row>>1)&3));
  // linear LDS dest, pre-swizzled source. ((64p+r)>>1)&3 == ((r>>1)&3) ✓.
  int srow = tid >> 2, kg = tid & 3;
  int ks = (kg ^ ((srow >> 1) & 3)) * 8;
  const ushort* srcA = A + (size_t)(m0 + srow) * D_K + ks;   // + 64p rows
  int wo = wave << 10;

#define STAGE_A(j) do {                                                  \
    char* sl_ = smem + ((j) % 3) * 24576 + wo;                           \
    GLOAD_LDS16(srcA + (j) * BK, sl_);                                   \
    GLOAD_LDS16(srcA + (size_t)64 * D_K + (j) * BK, sl_ + 4096);         \
    GLOAD_LDS16(srcA + (size_t)128 * D_K + (j) * BK, sl_ + 8192);        \
    GLOAD_LDS16(srcA + (size_t)192 * D_K + (j) * BK, sl_ + 12288);       \
  } while (0)

  // B reg-staging: thread covers row br = tid>>1, groups g0,g0+1 (16 floats,
  // 64 B contiguous in Wf). LDS B region: slot + 16 KB + br*64 + (g^swz)*16.
  int br = tid >> 1, g0 = (tid & 1) * 2;
  int bswz = (br >> 1) & 3;
  const float* srcBf = Wf + (size_t)(n0 + br) * D_K + g0 * 8;

#define LOADB(j, d0, d1, d2, d3) do {                    \
    const float* p_ = srcBf + (j) * BK;                  \
    d0 = gloadf4(p_); d1 = gloadf4(p_ + 4);              \
    d2 = gloadf4(p_ + 8); d3 = gloadf4(p_ + 12);         \
  } while (0)

#define WRITEB(j, d0, d1, d2, d3) do {                                        \
    char* bb_ = smem + ((j) % 3) * 24576 + 16384 + br * 64;                   \
    uint4 q0_, q1_;                                                           \
    q0_.x = cvtpk(d0[0], d0[1]); q0_.y = cvtpk(d0[2], d0[3]);                 \
    q0_.z = cvtpk(d1[0], d1[1]); q0_.w = cvtpk(d1[2], d1[3]);                 \
    q1_.x = cvtpk(d2[0], d2[1]); q1_.y = cvtpk(d2[2], d2[3]);                 \
    q1_.z = cvtpk(d3[0], d3[1]); q1_.w = cvtpk(d3[2], d3[3]);                 \
    *reinterpret_cast<uint4*>(bb_ + ((g0 ^ bswz) << 4)) = q0_;                \
    *reinterpret_cast<uint4*>(bb_ + (((g0 + 1) ^ bswz) << 4)) = q1_;          \
  } while (0)

  // fragment read indices (swizzled), ushort units within a slot.
  int kg0 = lane >> 4, l15 = lane & 15, lr = lane >> 4;
  int aIdx[8], bIdx[4];
#pragma unroll
  for (int m = 0; m < 8; ++m) {
    int r = wr * 128 + m * 16 + l15;
    aIdx[m] = r * 32 + ((kg0 ^ ((r >> 1) & 3)) << 3);
  }
#pragma unroll
  for (int n = 0; n < 4; ++n) {
    int r = wc * 64 + n * 16 + l15;
    bIdx[n] = 8192 + r * 32 + ((kg0 ^ ((r >> 1) & 3)) << 3);  // B at +16 KB
  }

  f32x4 acc[8][4] = {};

  // prologue: Bf32(0,1,2) -> regs; A(0,1) -> LDS; wait B0,B1; write B0.
  f32x4 b1a, b1b, b1c, b1d, b2a, b2b, b2c, b2d, t0, t1, t2, t3;
  LOADB(0, b1a, b1b, b1c, b1d);
  LOADB(1, b2a, b2b, b2c, b2d);
  LOADB(2, t0, t1, t2, t3);
  CFENCE();
  STAGE_A(0);
  STAGE_A(1);
  CFENCE();
  asm volatile("s_waitcnt vmcnt(12)" ::: "memory");  // B0,B1 landed
  WRITEB(0, b1a, b1b, b1c, b1d);
  // rotate: b1 <- B1, b2 <- B2
  b1a = b2a; b1b = b2b; b1c = b2c; b1d = b2d;
  b2a = t0; b2b = t1; b2c = t2; b2d = t3;

#pragma unroll
  for (int t = 0; t < NT; ++t) {
    // FIFO-derived wait ladder (A dist-2 gload_lds x4, Bf32 dist-3 x4/tile):
    // t=0: queue [B2,A0,A1] -> vmcnt(4) retires B2+A0. steady t=1..13: queue
    // [A(t),B(t+1),A(t+1),B(t+2)] -> vmcnt(8) retires A(t),B(t+1).
    // t=14: [A14,B15,A15] -> vmcnt(4). t=15: [A15] -> vmcnt(0).
    // lgkmcnt(0) makes prior iter's WRITEB visible; barrier aligns waves.
    if (t == 0) { WAIT_BAR_LG(4); }
    else if (t <= 13) { WAIT_BAR_LG(8); }
    else if (t == 14) { WAIT_BAR_LG(4); }
    else { WAIT_BAR_LG(0); }

    const ushort* sl = (const ushort*)(smem + (t % 3) * 24576);
    bf16x8 af[8], bf[4];
#pragma unroll
    for (int n = 0; n < 4; ++n) bf[n] = *reinterpret_cast<const bf16x8*>(&sl[bIdx[n]]);
#pragma unroll
    for (int m = 0; m < 8; ++m) af[m] = *reinterpret_cast<const bf16x8*>(&sl[aIdx[m]]);

    if (t + 2 < NT) STAGE_A(t + 2);  // slot (t+2)%3 == (t-1)%3: reads retired
    CFENCE();
    f32x4 n0r, n1r, n2r, n3r;
    if (t + 3 < NT) { LOADB(t + 3, n0r, n1r, n2r, n3r); }
    CFENCE();
    if (t + 1 < NT) { WRITEB(t + 1, b1a, b1b, b1c, b1d); }  // slot (t+1)%3==(t-2)%3

    __builtin_amdgcn_s_setprio(1);
#pragma unroll
    for (int m = 0; m < 8; ++m)
#pragma unroll
      for (int n = 0; n < 4; ++n)
        acc[m][n] = __builtin_amdgcn_mfma_f32_16x16x32_bf16(af[m], bf[n], acc[m][n], 0, 0, 0);
    __builtin_amdgcn_s_setprio(0);

    // rotate B reg pipeline (SSA via full unroll)
    b1a = b2a; b1b = b2b; b1c = b2c; b1d = b2d;
    if (t + 3 < NT) { b2a = n0r; b2b = n1r; b2c = n2r; b2d = n3r; }
  }
#undef STAGE_A
#undef LOADB
#undef WRITEB

  LBAR();  // all slot ds_reads retired; smem reusable as sC

  // LDS-transposed epilogue: 4 super-chunks of 64 rows x 128 cols via
  // sC[64][SCP]; full-line NT stores (r16 A/B: NT > plain by 10us).
  float* sC = reinterpret_cast<float*>(smem);
  float bj[4], rm[4];
#pragma unroll
  for (int n = 0; n < 4; ++n) {
    int col = n0 + wc * 64 + n * 16 + l15;
    bj[n] = bias[col];
    rm[n] = cmask[assign[col]];
  }
#pragma unroll
  for (int s = 0; s < 4; ++s) {
#pragma unroll
    for (int e = 0; e < 2; ++e) {
      int m = 2 * s + e;
      float4 qm = *reinterpret_cast<const float4*>(&qmask[m0 + wr * 128 + m * 16 + lr * 4]);
      int rl = wr * 32 + e * 16 + lr * 4;  // sC local row
#pragma unroll
      for (int n = 0; n < 4; ++n) {
        int cc = wc * 64 + n * 16 + l15;
        sC[(rl + 0) * SCP + cc] = (acc[m][n][0] + bj[n]) * qm.x * rm[n];
        sC[(rl + 1) * SCP + cc] = (acc[m][n][1] + bj[n]) * qm.y * rm[n];
        sC[(rl + 2) * SCP + cc] = (acc[m][n][2] + bj[n]) * qm.z * rm[n];
        sC[(rl + 3) * SCP + cc] = (acc[m][n][3] + bj[n]) * qm.w * rm[n];
      }
    }
    LBAR();
    f32x4 v[8];
#pragma unroll
    for (int i = 0; i < 8; ++i) {
      int rl = wave * 16 + i * 2 + (lane >> 5);
      v[i] = *reinterpret_cast<const f32x4*>(&sC[rl * SCP + (lane & 31) * 4]);
    }
    LBAR();
#pragma unroll
    for (int i = 0; i < 8; ++i) {
      int rl = wave * 16 + i * 2 + (lane >> 5);
      int grow = m0 + (rl >> 5) * 128 + s * 32 + ((rl >> 4) & 1) * 16 + (rl & 15);
      __builtin_nontemporal_store(
          v[i], reinterpret_cast<f32x4*>(&C[(size_t)grow * D_OUT + n0 + (lane & 31) * 4]));
    }
  }
}

extern "C" void kernel_launch(void* const* d_in, const int* in_sizes, int n_in,
                              void* d_out, int out_size, void* d_ws, size_t ws_size,
                              hipStream_t stream) {
  const float* input     = (const float*)d_in[0];
  const float* weight    = (const float*)d_in[1];
  const float* bias      = (const float*)d_in[2];
  const float* centroids = (const float*)d_in[3];
  const int*   assign    = (const int*)d_in[4];
  float* out = (float*)d_out;

  // ws layout (bytes):
  //   A_bf16 : 0          (4 MiB)
  //   qmask  : 20,971,520 (16 KB)
  //   cmask  : 20,987,904 (1 KB)
  //   centT4 : 21,000,192 (512 KB)
  char* ws = (char*)d_ws;
  ushort* A_bf   = (ushort*)ws;
  float*  qmask  = (float*)(ws + 20971520);
  float*  cmask  = (float*)(ws + 20987904);
  float4* centT4 = (float4*)(ws + 21000192);

  cent_kernel<<<128, 256, 0, stream>>>(centroids, centT4, cmask);
  routing_kernel<<<N_Q / 8, 256, 0, stream>>>(input, centT4, qmask, cmask, A_bf);
  gemm_masked_kernel<<<(N_Q / BM) * (D_OUT / BN), 256, 0, stream>>>(
      A_bf, weight, bias, assign, qmask, cmask, out);
}

// Round 18
// 153.436 us; speedup vs baseline: 1.0238x; 1.0238x over previous
//
#include <hip/hip_runtime.h>
#include <stdint.h>

#define N_Q    4096
#define D_K    512
#define D_OUT  16384
#define NCLUST 256

// GEMM: round-15 verbatim (133.0us best, replicated): 256x128 tile, BK=32,
// 4 waves (2M x 2N), per-wave 128x64 (acc 8x4), ring-3 24KB slots = 72 KB ->
// 2 WG/CU, counted WAIT_BAR(6), T2 swizzle, setprio, XCD panel mapping,
// LDS-transposed full-line NT epilogue (NT>plain by r16 A/B; in-GEMM W-cvt
// regressed r17; 8-phase r12, A-direct r9/r10, ring-2 r11/r13 all regressed).
// Round-18 front-end harvest: (1) prep W-writes XCD-aligned to the GEMM's
// ntile->XCD map (W_bf read from local L2, not HBM); (2) routing 16 q/block
// (centroid L2 traffic halves 268->134 MB).
#define BM 256
#define BN 128
#define BK 32
#define NT (D_K / BK)   // 16 K-tiles
#define SCP 132         // sC row stride in floats (non-pow2: conflict-free)

typedef __attribute__((ext_vector_type(4))) float f32x4;
typedef __attribute__((ext_vector_type(8))) short bf16x8;

__device__ __forceinline__ uint32_t f2bf(float f) {
  uint32_t u = __float_as_uint(f);
  u += 0x7FFFu + ((u >> 16) & 1u);
  return u >> 16;
}

#define GLOAD_LDS16(g, l)                                         \
  __builtin_amdgcn_global_load_lds(                               \
      (const __attribute__((address_space(1))) void*)(g),         \
      (__attribute__((address_space(3))) void*)(l), 16, 0, 0)

#define WAIT_BAR(N) asm volatile("s_waitcnt vmcnt(" #N ")\n\ts_barrier" ::: "memory")
#define LBAR() asm volatile("s_waitcnt lgkmcnt(0)\n\ts_barrier" ::: "memory")

// merged: W f32->bf16 convert (blocks 0..4095, XCD-aligned) + centroid
// transpose + cmask zero (blocks 4096..4223)
__global__ __launch_bounds__(256) void prep_kernel(const float* __restrict__ weight,
                                                   ushort* __restrict__ W_bf,
                                                   const float* __restrict__ cent,
                                                   float4* __restrict__ centT4,
                                                   float* __restrict__ cmask) {
  int b = blockIdx.x;
  if (b < 4096) {
    // XCD-align: physical block pb runs on XCD pb&7 (round-robin dispatch);
    // logical work lb covers W rows [4lb,4lb+4); GEMM's ntile->XCD map gives
    // XCD x the rows [2048x,2048x+2048). lb=(pb&7)*512+(pb>>3) makes the
    // writer's XCD == the reader's XCD -> W_bf stays in the right L2.
    int lb = (b & 7) * 512 + (b >> 3);
    int i = lb * 256 + threadIdx.x;
    const float4* s = reinterpret_cast<const float4*>(weight) + (size_t)i * 2;
    float4 v0 = s[0], v1 = s[1];
    uint4 o;
    o.x = f2bf(v0.x) | (f2bf(v0.y) << 16);
    o.y = f2bf(v0.z) | (f2bf(v0.w) << 16);
    o.z = f2bf(v1.x) | (f2bf(v1.y) << 16);
    o.w = f2bf(v1.z) | (f2bf(v1.w) << 16);
    reinterpret_cast<uint4*>(W_bf)[i] = o;
  } else {
    int bb = b - 4096;
    if (bb == 0) cmask[threadIdx.x] = 0.0f;
    int idx = bb * 256 + threadIdx.x;
    int k4 = idx & 127, c = idx >> 7;
    float4 v = *reinterpret_cast<const float4*>(&cent[(size_t)c * D_K + k4 * 4]);
    centT4[(size_t)k4 * NCLUST + c] = v;
  }
}

// 16 queries/block (256 blocks): halves centT4 L2 traffic vs 8 q/block.
// Thread t owns centroid t; fused A f32->bf16 convert (32 elems/thread).
// f32 routing math throughout (threshold booleans must not flip).
__global__ __launch_bounds__(256) void routing_kernel(const float* __restrict__ input,
                                                      const float4* __restrict__ centT4,
                                                      float* __restrict__ qmask,
                                                      float* __restrict__ cmask,
                                                      ushort* __restrict__ A_bf) {
  __shared__ float lgs[16][NCLUST];
  int c = threadIdx.x;
  int q0 = blockIdx.x * 16;
  const float* __restrict__ inp = input + (size_t)q0 * D_K;

  {  // fused A-convert: 16 rows * 512 = 8192 elems, 32 per thread
    const float4* s4 = reinterpret_cast<const float4*>(inp) + c * 8;
    uint4* dst = reinterpret_cast<uint4*>(A_bf + (size_t)q0 * D_K) + c * 4;
#pragma unroll
    for (int j = 0; j < 4; ++j) {
      float4 x0 = s4[j * 2], x1 = s4[j * 2 + 1];
      uint4 o;
      o.x = f2bf(x0.x) | (f2bf(x0.y) << 16);
      o.y = f2bf(x0.z) | (f2bf(x0.w) << 16);
      o.z = f2bf(x1.x) | (f2bf(x1.y) << 16);
      o.w = f2bf(x1.z) | (f2bf(x1.w) << 16);
      dst[j] = o;
    }
  }

  float acc[16] = {};
  for (int k4 = 0; k4 < D_K / 4; ++k4) {
    float4 v = centT4[(size_t)k4 * NCLUST + c];
#pragma unroll
    for (int q = 0; q < 16; ++q) {
      float4 r = *reinterpret_cast<const float4*>(&inp[q * D_K + k4 * 4]);  // uniform addr
      acc[q] += v.x * r.x + v.y * r.y + v.z * r.z + v.w * r.w;
    }
  }
#pragma unroll
  for (int q = 0; q < 16; ++q) lgs[q][c] = acc[q] * 10.0f;  // /TEMPERATURE
  __syncthreads();

  int wave = c >> 6, lane = c & 63;
#pragma unroll
  for (int qq = 0; qq < 4; ++qq) {
    int q = wave * 4 + qq;
    float4 lv = *reinterpret_cast<const float4*>(&lgs[q][lane * 4]);
    float m = fmaxf(fmaxf(lv.x, lv.y), fmaxf(lv.z, lv.w));
#pragma unroll
    for (int off = 32; off > 0; off >>= 1) m = fmaxf(m, __shfl_xor(m, off));
    float e0 = expf(lv.x - m), e1 = expf(lv.y - m), e2 = expf(lv.z - m), e3 = expf(lv.w - m);
    float s = e0 + e1 + e2 + e3;
#pragma unroll
    for (int off = 32; off > 0; off >>= 1) s += __shfl_xor(s, off);
    float thr = 0.01f * s;
    bool a0 = e0 > thr, a1 = e1 > thr, a2 = e2 > thr, a3 = e3 > thr;
    if (a0) cmask[lane * 4 + 0] = 1.0f;  // benign races: all writers store 1.0
    if (a1) cmask[lane * 4 + 1] = 1.0f;
    if (a2) cmask[lane * 4 + 2] = 1.0f;
    if (a3) cmask[lane * 4 + 3] = 1.0f;
    unsigned long long any = __ballot(a0 | a1 | a2 | a3);
    if (lane == 0) qmask[q0 + q] = any ? 1.0f : 0.0f;
  }
}

__global__ __launch_bounds__(256, 2) void gemm_masked_kernel(
    const ushort* __restrict__ A, const ushort* __restrict__ W,
    const float* __restrict__ bias, const int* __restrict__ assign,
    const float* __restrict__ qmask, const float* __restrict__ cmask,
    float* __restrict__ C) {
  // LDS 72 KB: 3 slots of 24 KB = {A 16 KB (4 x 4KB row-groups) | B 8 KB}.
  // Epilogue reuses front 33.8 KB as sC[64][SCP]. 2 WG/CU.
  __shared__ __align__(16) char smem[73728];

  int tid = threadIdx.x;
  int wave = tid >> 6, lane = tid & 63;

  // XCD mapping: xcd = bid&7 owns ntiles [16x,16x+16); ntile fast within XCD
  // (2 MB W-set L2-resident, now pre-warmed by prep's aligned writes).
  int bid = blockIdx.x;
  int idx = bid >> 3;                         // 0..255
  int ntile = (bid & 7) * 16 + (idx & 15);    // 0..127
  int mtile = idx >> 4;                       // 0..15
  int m0 = mtile * BM, n0 = ntile * BN;

  int wr = wave >> 1, wc = wave & 1;  // 2x2 wave grid; per-wave C: 128x64

  // staging: LDS (row,kg) <- global (row, kg ^ ((row>>1)&3)); linear LDS dest,
  // pre-swizzled per-lane source (rule #21). ((64p+r)>>1)&3 == ((r>>1)&3) ✓.
  int srow = tid >> 2, kg = tid & 3;
  int ks = (kg ^ ((srow >> 1) & 3)) * 8;
  const ushort* srcA = A + (size_t)(m0 + srow) * D_K + ks;   // + 64p rows, p=0..3
  const ushort* srcB = W + (size_t)(n0 + srow) * D_K + ks;   // + 64p rows, p=0..1
  int wo = wave << 10;  // wave's 1 KB chunk within each 4 KB row-group

#define STAGE(j) do {                                                    \
    char* sl_ = smem + ((j) % 3) * 24576 + wo;                           \
    GLOAD_LDS16(srcA + (j) * BK, sl_);                                   \
    GLOAD_LDS16(srcA + (size_t)64 * D_K + (j) * BK, sl_ + 4096);         \
    GLOAD_LDS16(srcA + (size_t)128 * D_K + (j) * BK, sl_ + 8192);        \
    GLOAD_LDS16(srcA + (size_t)192 * D_K + (j) * BK, sl_ + 12288);       \
    GLOAD_LDS16(srcB + (j) * BK, sl_ + 16384);                           \
    GLOAD_LDS16(srcB + (size_t)64 * D_K + (j) * BK, sl_ + 20480);        \
  } while (0)

  // fragment read indices (swizzled), ushort units within a slot.
  int kg0 = lane >> 4, l15 = lane & 15, lr = lane >> 4;
  int aIdx[8], bIdx[4];
#pragma unroll
  for (int m = 0; m < 8; ++m) {
    int r = wr * 128 + m * 16 + l15;
    aIdx[m] = r * 32 + ((kg0 ^ ((r >> 1) & 3)) << 3);
  }
#pragma unroll
  for (int n = 0; n < 4; ++n) {
    int r = wc * 64 + n * 16 + l15;
    bIdx[n] = 8192 + r * 32 + ((kg0 ^ ((r >> 1) & 3)) << 3);  // B at +16 KB
  }

  f32x4 acc[8][4] = {};

  STAGE(0);
  STAGE(1);

#pragma unroll
  for (int t = 0; t < NT; ++t) {
    // loop top: tile t's 6 loads are oldest (12 outstanding with t+1's 6);
    // WAIT_BAR(6) retires exactly tile t, t+1 stays in flight.
    if (t < NT - 1) { WAIT_BAR(6); } else { WAIT_BAR(0); }

    const ushort* sl = (const ushort*)(smem + (t % 3) * 24576);
    bf16x8 af[8], bf[4];
#pragma unroll
    for (int n = 0; n < 4; ++n) bf[n] = *reinterpret_cast<const bf16x8*>(&sl[bIdx[n]]);
#pragma unroll
    for (int m = 0; m < 8; ++m) af[m] = *reinterpret_cast<const bf16x8*>(&sl[aIdx[m]]);
    if (t + 2 < NT) STAGE(t + 2);  // slot (t+2)%3 == (t-1)%3: reads retired pre-barrier

    __builtin_amdgcn_s_setprio(1);
#pragma unroll
    for (int m = 0; m < 8; ++m)
#pragma unroll
      for (int n = 0; n < 4; ++n)
        acc[m][n] = __builtin_amdgcn_mfma_f32_16x16x32_bf16(af[m], bf[n], acc[m][n], 0, 0, 0);
    __builtin_amdgcn_s_setprio(0);
    // closing barrier is next iteration's WAIT_BAR (or loop exit)
  }
#undef STAGE

  LBAR();  // all slot ds_reads retired; smem reusable as sC

  // LDS-transposed epilogue: 4 super-chunks of 64 rows x 128 cols via
  // sC[64][SCP]; full-line NT stores (r16 A/B: NT > plain by 10us).
  float* sC = reinterpret_cast<float*>(smem);
  float bj[4], rm[4];
#pragma unroll
  for (int n = 0; n < 4; ++n) {
    int col = n0 + wc * 64 + n * 16 + l15;
    bj[n] = bias[col];
    rm[n] = cmask[assign[col]];
  }
#pragma unroll
  for (int s = 0; s < 4; ++s) {
#pragma unroll
    for (int e = 0; e < 2; ++e) {
      int m = 2 * s + e;
      float4 qm = *reinterpret_cast<const float4*>(&qmask[m0 + wr * 128 + m * 16 + lr * 4]);
      int rl = wr * 32 + e * 16 + lr * 4;  // sC local row
#pragma unroll
      for (int n = 0; n < 4; ++n) {
        int cc = wc * 64 + n * 16 + l15;
        sC[(rl + 0) * SCP + cc] = (acc[m][n][0] + bj[n]) * qm.x * rm[n];
        sC[(rl + 1) * SCP + cc] = (acc[m][n][1] + bj[n]) * qm.y * rm[n];
        sC[(rl + 2) * SCP + cc] = (acc[m][n][2] + bj[n]) * qm.z * rm[n];
        sC[(rl + 3) * SCP + cc] = (acc[m][n][3] + bj[n]) * qm.w * rm[n];
      }
    }
    LBAR();
    f32x4 v[8];
#pragma unroll
    for (int i = 0; i < 8; ++i) {
      int rl = wave * 16 + i * 2 + (lane >> 5);
      v[i] = *reinterpret_cast<const f32x4*>(&sC[rl * SCP + (lane & 31) * 4]);
    }
    LBAR();
#pragma unroll
    for (int i = 0; i < 8; ++i) {
      int rl = wave * 16 + i * 2 + (lane >> 5);
      int grow = m0 + (rl >> 5) * 128 + s * 32 + ((rl >> 4) & 1) * 16 + (rl & 15);
      __builtin_nontemporal_store(
          v[i], reinterpret_cast<f32x4*>(&C[(size_t)grow * D_OUT + n0 + (lane & 31) * 4]));
    }
  }
}

extern "C" void kernel_launch(void* const* d_in, const int* in_sizes, int n_in,
                              void* d_out, int out_size, void* d_ws, size_t ws_size,
                              hipStream_t stream) {
  const float* input     = (const float*)d_in[0];
  const float* weight    = (const float*)d_in[1];
  const float* bias      = (const float*)d_in[2];
  const float* centroids = (const float*)d_in[3];
  const int*   assign    = (const int*)d_in[4];
  float* out = (float*)d_out;

  // ws layout (bytes):
  //   A_bf16 : 0          (4 MiB)
  //   W_bf16 : 4,194,304  (16 MiB)
  //   qmask  : 20,971,520 (16 KB)
  //   cmask  : 20,987,904 (1 KB)
  //   centT4 : 21,000,192 (512 KB)
  char* ws = (char*)d_ws;
  ushort* A_bf   = (ushort*)ws;
  ushort* W_bf   = (ushort*)(ws + 4194304);
  float*  qmask  = (float*)(ws + 20971520);
  float*  cmask  = (float*)(ws + 20987904);
  float4* centT4 = (float4*)(ws + 21000192);

  prep_kernel<<<4224, 256, 0, stream>>>(weight, W_bf, centroids, centT4, cmask);
  routing_kernel<<<N_Q / 16, 256, 0, stream>>>(input, centT4, qmask, cmask, A_bf);
  gemm_masked_kernel<<<(N_Q / BM) * (D_OUT / BN), 256, 0, stream>>>(
      A_bf, W_bf, bias, assign, qmask, cmask, out);
}

// Round 19
// 132.933 us; speedup vs baseline: 1.1817x; 1.1542x over previous
//
#include <hip/hip_runtime.h>
#include <stdint.h>

#define N_Q    4096
#define D_K    512
#define D_OUT  16384
#define NCLUST 256

// FINAL (round-15 configuration, replicated best: 133.0/133.1 us).
// GEMM: 256x128 tile, BK=32, 4 waves (2M x 2N), per-wave 128x64 (acc 8x4).
// Ring-3 slots of 24 KB = 72 KB -> 2 WG/CU, counted WAIT_BAR(6) (never drains
// mid-loop), T2 swizzle via pre-swizzled global source, setprio, XCD panel
// mapping, LDS-transposed full-line NT epilogue (NT>plain: r16 A/B).
// Eliminated by measurement: 8-phase (r12 +19us: 1WG serializes C-drain),
// A-direct reg loads (r9/r10: latency-bound, schedule-insensitive),
// ring-2 at 4/5 WG (r11 spill, r13 drain-stall), in-GEMM W-cvt (r17 -24us),
// fused front-end (r14 -6.5us), plain stores (r16 -10us), XCD-prep+16q
// routing (r18 -20us). This is the empirical optimum of the explored space.
#define BM 256
#define BN 128
#define BK 32
#define NT (D_K / BK)   // 16 K-tiles
#define SCP 132         // sC row stride in floats (non-pow2: conflict-free)

typedef __attribute__((ext_vector_type(4))) float f32x4;
typedef __attribute__((ext_vector_type(8))) short bf16x8;

__device__ __forceinline__ uint32_t f2bf(float f) {
  uint32_t u = __float_as_uint(f);
  u += 0x7FFFu + ((u >> 16) & 1u);
  return u >> 16;
}

#define GLOAD_LDS16(g, l)                                         \
  __builtin_amdgcn_global_load_lds(                               \
      (const __attribute__((address_space(1))) void*)(g),         \
      (__attribute__((address_space(3))) void*)(l), 16, 0, 0)

#define WAIT_BAR(N) asm volatile("s_waitcnt vmcnt(" #N ")\n\ts_barrier" ::: "memory")
#define LBAR() asm volatile("s_waitcnt lgkmcnt(0)\n\ts_barrier" ::: "memory")

// merged: W f32->bf16 convert (blocks 0..4095) + centroid transpose (4096..4223)
__global__ __launch_bounds__(256) void prep_kernel(const float* __restrict__ weight,
                                                   ushort* __restrict__ W_bf,
                                                   const float* __restrict__ cent,
                                                   float4* __restrict__ centT4,
                                                   float* __restrict__ cmask) {
  int b = blockIdx.x;
  if (b < (D_OUT * D_K / 8) / 256) {
    int i = b * 256 + threadIdx.x;
    const float4* s = reinterpret_cast<const float4*>(weight) + (size_t)i * 2;
    float4 v0 = s[0], v1 = s[1];
    uint4 o;
    o.x = f2bf(v0.x) | (f2bf(v0.y) << 16);
    o.y = f2bf(v0.z) | (f2bf(v0.w) << 16);
    o.z = f2bf(v1.x) | (f2bf(v1.y) << 16);
    o.w = f2bf(v1.z) | (f2bf(v1.w) << 16);
    reinterpret_cast<uint4*>(W_bf)[i] = o;
  } else {
    int bb = b - (D_OUT * D_K / 8) / 256;
    if (bb == 0) cmask[threadIdx.x] = 0.0f;
    int idx = bb * 256 + threadIdx.x;
    int k4 = idx & 127, c = idx >> 7;
    float4 v = *reinterpret_cast<const float4*>(&cent[(size_t)c * D_K + k4 * 4]);
    centT4[(size_t)k4 * NCLUST + c] = v;
  }
}

// 8 queries/block; thread t owns centroid t; fused A f32->bf16 convert.
// f32 routing math throughout (threshold booleans must not flip).
__global__ __launch_bounds__(256) void routing_kernel(const float* __restrict__ input,
                                                      const float4* __restrict__ centT4,
                                                      float* __restrict__ qmask,
                                                      float* __restrict__ cmask,
                                                      ushort* __restrict__ A_bf) {
  __shared__ float lgs[8][NCLUST];
  int c = threadIdx.x;
  int q0 = blockIdx.x * 8;
  const float* __restrict__ inp = input + (size_t)q0 * D_K;

  {
    const float4* s4 = reinterpret_cast<const float4*>(inp) + c * 4;
    float4 x0 = s4[0], x1 = s4[1], x2 = s4[2], x3 = s4[3];
    uint4 o0, o1;
    o0.x = f2bf(x0.x) | (f2bf(x0.y) << 16);
    o0.y = f2bf(x0.z) | (f2bf(x0.w) << 16);
    o0.z = f2bf(x1.x) | (f2bf(x1.y) << 16);
    o0.w = f2bf(x1.z) | (f2bf(x1.w) << 16);
    o1.x = f2bf(x2.x) | (f2bf(x2.y) << 16);
    o1.y = f2bf(x2.z) | (f2bf(x2.w) << 16);
    o1.z = f2bf(x3.x) | (f2bf(x3.y) << 16);
    o1.w = f2bf(x3.z) | (f2bf(x3.w) << 16);
    uint4* dst = reinterpret_cast<uint4*>(A_bf + (size_t)q0 * D_K);
    dst[c * 2] = o0;
    dst[c * 2 + 1] = o1;
  }

  float acc[8] = {0, 0, 0, 0, 0, 0, 0, 0};
  for (int k4 = 0; k4 < D_K / 4; ++k4) {
    float4 v = centT4[(size_t)k4 * NCLUST + c];
#pragma unroll
    for (int q = 0; q < 8; ++q) {
      float4 r = *reinterpret_cast<const float4*>(&inp[q * D_K + k4 * 4]);  // uniform addr
      acc[q] += v.x * r.x + v.y * r.y + v.z * r.z + v.w * r.w;
    }
  }
#pragma unroll
  for (int q = 0; q < 8; ++q) lgs[q][c] = acc[q] * 10.0f;  // /TEMPERATURE
  __syncthreads();

  int wave = c >> 6, lane = c & 63;
#pragma unroll
  for (int qq = 0; qq < 2; ++qq) {
    int q = wave * 2 + qq;
    float4 lv = *reinterpret_cast<const float4*>(&lgs[q][lane * 4]);
    float m = fmaxf(fmaxf(lv.x, lv.y), fmaxf(lv.z, lv.w));
#pragma unroll
    for (int off = 32; off > 0; off >>= 1) m = fmaxf(m, __shfl_xor(m, off));
    float e0 = expf(lv.x - m), e1 = expf(lv.y - m), e2 = expf(lv.z - m), e3 = expf(lv.w - m);
    float s = e0 + e1 + e2 + e3;
#pragma unroll
    for (int off = 32; off > 0; off >>= 1) s += __shfl_xor(s, off);
    float thr = 0.01f * s;
    bool a0 = e0 > thr, a1 = e1 > thr, a2 = e2 > thr, a3 = e3 > thr;
    if (a0) cmask[lane * 4 + 0] = 1.0f;  // benign races: all writers store 1.0
    if (a1) cmask[lane * 4 + 1] = 1.0f;
    if (a2) cmask[lane * 4 + 2] = 1.0f;
    if (a3) cmask[lane * 4 + 3] = 1.0f;
    unsigned long long any = __ballot(a0 | a1 | a2 | a3);
    if (lane == 0) qmask[q0 + q] = any ? 1.0f : 0.0f;
  }
}

__global__ __launch_bounds__(256, 2) void gemm_masked_kernel(
    const ushort* __restrict__ A, const ushort* __restrict__ W,
    const float* __restrict__ bias, const int* __restrict__ assign,
    const float* __restrict__ qmask, const float* __restrict__ cmask,
    float* __restrict__ C) {
  // LDS 72 KB: 3 slots of 24 KB = {A 16 KB (4 x 4KB row-groups) | B 8 KB}.
  // Epilogue reuses front 33.8 KB as sC[64][SCP]. 2 WG/CU.
  __shared__ __align__(16) char smem[73728];

  int tid = threadIdx.x;
  int wave = tid >> 6, lane = tid & 63;

  // XCD mapping: xcd = bid&7 owns ntiles [16x,16x+16); ntile fast within XCD
  // (2 MB W-set L2-resident). 2048 = 8*16*16 -> bijective.
  int bid = blockIdx.x;
  int idx = bid >> 3;                         // 0..255
  int ntile = (bid & 7) * 16 + (idx & 15);    // 0..127
  int mtile = idx >> 4;                       // 0..15
  int m0 = mtile * BM, n0 = ntile * BN;

  int wr = wave >> 1, wc = wave & 1;  // 2x2 wave grid; per-wave C: 128x64

  // staging: LDS (row,kg) <- global (row, kg ^ ((row>>1)&3)); linear LDS dest,
  // pre-swizzled per-lane source (rule #21). ((64p+r)>>1)&3 == ((r>>1)&3) ✓.
  int srow = tid >> 2, kg = tid & 3;
  int ks = (kg ^ ((srow >> 1) & 3)) * 8;
  const ushort* srcA = A + (size_t)(m0 + srow) * D_K + ks;   // + 64p rows, p=0..3
  const ushort* srcB = W + (size_t)(n0 + srow) * D_K + ks;   // + 64p rows, p=0..1
  int wo = wave << 10;  // wave's 1 KB chunk within each 4 KB row-group

#define STAGE(j) do {                                                    \
    char* sl_ = smem + ((j) % 3) * 24576 + wo;                           \
    GLOAD_LDS16(srcA + (j) * BK, sl_);                                   \
    GLOAD_LDS16(srcA + (size_t)64 * D_K + (j) * BK, sl_ + 4096);         \
    GLOAD_LDS16(srcA + (size_t)128 * D_K + (j) * BK, sl_ + 8192);        \
    GLOAD_LDS16(srcA + (size_t)192 * D_K + (j) * BK, sl_ + 12288);       \
    GLOAD_LDS16(srcB + (j) * BK, sl_ + 16384);                           \
    GLOAD_LDS16(srcB + (size_t)64 * D_K + (j) * BK, sl_ + 20480);        \
  } while (0)

  // fragment read indices (swizzled), ushort units within a slot.
  int kg0 = lane >> 4, l15 = lane & 15, lr = lane >> 4;
  int aIdx[8], bIdx[4];
#pragma unroll
  for (int m = 0; m < 8; ++m) {
    int r = wr * 128 + m * 16 + l15;
    aIdx[m] = r * 32 + ((kg0 ^ ((r >> 1) & 3)) << 3);
  }
#pragma unroll
  for (int n = 0; n < 4; ++n) {
    int r = wc * 64 + n * 16 + l15;
    bIdx[n] = 8192 + r * 32 + ((kg0 ^ ((r >> 1) & 3)) << 3);  // B at +16 KB
  }

  f32x4 acc[8][4] = {};

  STAGE(0);
  STAGE(1);

#pragma unroll
  for (int t = 0; t < NT; ++t) {
    // loop top: tile t's 6 loads are oldest (12 outstanding with t+1's 6);
    // WAIT_BAR(6) retires exactly tile t, t+1 stays in flight.
    if (t < NT - 1) { WAIT_BAR(6); } else { WAIT_BAR(0); }

    const ushort* sl = (const ushort*)(smem + (t % 3) * 24576);
    bf16x8 af[8], bf[4];
#pragma unroll
    for (int n = 0; n < 4; ++n) bf[n] = *reinterpret_cast<const bf16x8*>(&sl[bIdx[n]]);
#pragma unroll
    for (int m = 0; m < 8; ++m) af[m] = *reinterpret_cast<const bf16x8*>(&sl[aIdx[m]]);
    if (t + 2 < NT) STAGE(t + 2);  // slot (t+2)%3 == (t-1)%3: reads retired pre-barrier

    __builtin_amdgcn_s_setprio(1);
#pragma unroll
    for (int m = 0; m < 8; ++m)
#pragma unroll
      for (int n = 0; n < 4; ++n)
        acc[m][n] = __builtin_amdgcn_mfma_f32_16x16x32_bf16(af[m], bf[n], acc[m][n], 0, 0, 0);
    __builtin_amdgcn_s_setprio(0);
    // closing barrier is next iteration's WAIT_BAR (or loop exit)
  }
#undef STAGE

  LBAR();  // all slot ds_reads retired; smem reusable as sC

  // LDS-transposed epilogue: 4 super-chunks of 64 rows x 128 cols via
  // sC[64][SCP]; full-line NT stores (r16 A/B: NT > plain by 10us).
  float* sC = reinterpret_cast<float*>(smem);
  float bj[4], rm[4];
#pragma unroll
  for (int n = 0; n < 4; ++n) {
    int col = n0 + wc * 64 + n * 16 + l15;
    bj[n] = bias[col];
    rm[n] = cmask[assign[col]];
  }
#pragma unroll
  for (int s = 0; s < 4; ++s) {
#pragma unroll
    for (int e = 0; e < 2; ++e) {
      int m = 2 * s + e;
      float4 qm = *reinterpret_cast<const float4*>(&qmask[m0 + wr * 128 + m * 16 + lr * 4]);
      int rl = wr * 32 + e * 16 + lr * 4;  // sC local row
#pragma unroll
      for (int n = 0; n < 4; ++n) {
        int cc = wc * 64 + n * 16 + l15;
        sC[(rl + 0) * SCP + cc] = (acc[m][n][0] + bj[n]) * qm.x * rm[n];
        sC[(rl + 1) * SCP + cc] = (acc[m][n][1] + bj[n]) * qm.y * rm[n];
        sC[(rl + 2) * SCP + cc] = (acc[m][n][2] + bj[n]) * qm.z * rm[n];
        sC[(rl + 3) * SCP + cc] = (acc[m][n][3] + bj[n]) * qm.w * rm[n];
      }
    }
    LBAR();
    f32x4 v[8];
#pragma unroll
    for (int i = 0; i < 8; ++i) {
      int rl = wave * 16 + i * 2 + (lane >> 5);
      v[i] = *reinterpret_cast<const f32x4*>(&sC[rl * SCP + (lane & 31) * 4]);
    }
    LBAR();
#pragma unroll
    for (int i = 0; i < 8; ++i) {
      int rl = wave * 16 + i * 2 + (lane >> 5);
      int grow = m0 + (rl >> 5) * 128 + s * 32 + ((rl >> 4) & 1) * 16 + (rl & 15);
      __builtin_nontemporal_store(
          v[i], reinterpret_cast<f32x4*>(&C[(size_t)grow * D_OUT + n0 + (lane & 31) * 4]));
    }
  }
}

extern "C" void kernel_launch(void* const* d_in, const int* in_sizes, int n_in,
                              void* d_out, int out_size, void* d_ws, size_t ws_size,
                              hipStream_t stream) {
  const float* input     = (const float*)d_in[0];
  const float* weight    = (const float*)d_in[1];
  const float* bias      = (const float*)d_in[2];
  const float* centroids = (const float*)d_in[3];
  const int*   assign    = (const int*)d_in[4];
  float* out = (float*)d_out;

  // ws layout (bytes):
  //   A_bf16 : 0          (4 MiB)
  //   W_bf16 : 4,194,304  (16 MiB)
  //   qmask  : 20,971,520 (16 KB)
  //   cmask  : 20,987,904 (1 KB)
  //   centT4 : 21,000,192 (512 KB)
  char* ws = (char*)d_ws;
  ushort* A_bf   = (ushort*)ws;
  ushort* W_bf   = (ushort*)(ws + 4194304);
  float*  qmask  = (float*)(ws + 20971520);
  float*  cmask  = (float*)(ws + 20987904);
  float4* centT4 = (float4*)(ws + 21000192);

  prep_kernel<<<4224, 256, 0, stream>>>(weight, W_bf, centroids, centT4, cmask);
  routing_kernel<<<N_Q / 8, 256, 0, stream>>>(input, centT4, qmask, cmask, A_bf);
  gemm_masked_kernel<<<(N_Q / BM) * (D_OUT / BN), 256, 0, stream>>>(
      A_bf, W_bf, bias, assign, qmask, cmask, out);
}